// Round 1
// baseline (5017.236 us; speedup 1.0000x reference)
//
#include <hip/hip_runtime.h>
#include <math.h>

// Model constants
#define BL   2048   // B*L = 4*512
#define LSEQ 512
#define NB   4
#define DMOD 256
#define DIN  512
#define NST  16
#define DFF  682

__device__ __forceinline__ float sigmoidf_(float x) { return 1.f / (1.f + __expf(-x)); }
__device__ __forceinline__ float siluf_(float x) { return x / (1.f + __expf(-x)); }

// ---------------- DAIN stats (single block) ----------------
__global__ __launch_bounds__(1024) void dain_k(
    const float* __restrict__ src, const float* __restrict__ Wm,
    const float* __restrict__ Ws, const float* __restrict__ Wg,
    const float* __restrict__ bg, float* __restrict__ stats) {
  __shared__ float part[1024];
  __shared__ float avg_s[128], sub_s[128], std_s[128], mn_s[128], inv_s[128];
  int tid = threadIdx.x;
  int p = tid >> 3, j = tid & 7;
  int b = p >> 5, f = p & 31;
  float s = 0.f;
  for (int l = j * 64; l < j * 64 + 64; ++l) s += src[((size_t)b * LSEQ + l) * 32 + f];
  part[tid] = s;
  __syncthreads();
  if (tid < 128) { float a = 0; for (int k = 0; k < 8; k++) a += part[tid * 8 + k]; avg_s[tid] = a * (1.f / 512.f); }
  __syncthreads();
  if (tid < 128) {
    int bb = tid >> 5, ff = tid & 31;
    float a = 0; for (int g = 0; g < 32; g++) a += avg_s[bb * 32 + g] * Wm[ff * 32 + g];
    sub_s[tid] = a;
  }
  __syncthreads();
  float sub = sub_s[p];
  s = 0.f;
  for (int l = j * 64; l < j * 64 + 64; ++l) {
    float v = src[((size_t)b * LSEQ + l) * 32 + f] - sub; s += v * v;
  }
  part[tid] = s;
  __syncthreads();
  if (tid < 128) { float a = 0; for (int k = 0; k < 8; k++) a += part[tid * 8 + k]; std_s[tid] = sqrtf(a * (1.f / 512.f)); }
  __syncthreads();
  if (tid < 128) {
    int bb = tid >> 5, ff = tid & 31;
    float a = 0; for (int g = 0; g < 32; g++) a += std_s[bb * 32 + g] * Ws[ff * 32 + g];
    if (a <= 1e-8f) a = 1.f;
    inv_s[tid] = 1.f / a;
    mn_s[tid] = (avg_s[tid] - sub_s[tid]) / a;
  }
  __syncthreads();
  if (tid < 128) {
    int bb = tid >> 5, ff = tid & 31;
    float a = bg[ff]; for (int g = 0; g < 32; g++) a += mn_s[bb * 32 + g] * Wg[ff * 32 + g];
    float gate = sigmoidf_(a);
    float scl = gate * inv_s[tid];
    stats[tid] = scl;
    stats[128 + tid] = sub_s[tid] * scl;
  }
}

// ---------------- embed: market + tproj -> h ----------------
__global__ __launch_bounds__(256) void embed_k(
    const float* __restrict__ src, const float* __restrict__ tau,
    const float* __restrict__ stats, const float* __restrict__ membW,
    const float* __restrict__ membB, const float* __restrict__ tw0,
    const float* __restrict__ tb0, const float* __restrict__ tw,
    const float* __restrict__ tb, const float* __restrict__ tprojW,
    const float* __restrict__ tprojB, float* __restrict__ h) {
  int token = blockIdx.x;
  int b = token >> 9;
  int t = threadIdx.x;
  __shared__ float xs[32], te[32];
  if (t < 32) {
    float scl = stats[b * 32 + t], shf = stats[128 + b * 32 + t];
    xs[t] = src[(size_t)token * 32 + t] * scl - shf;
  } else if (t < 64) {
    int j = t - 32;
    const float* tr = tau + (size_t)token * 8;
    float a;
    if (j < 31) { a = tb[j]; for (int k = 0; k < 8; k++) a += tr[k] * tw[k * 31 + j]; a = sinf(a); }
    else        { a = tb0[0]; for (int k = 0; k < 8; k++) a += tr[k] * tw0[k]; }
    te[j] = a;
  }
  __syncthreads();
  float acc;
  if (t < 128) {
    acc = membB[t];
    for (int f = 0; f < 32; f++) acc += xs[f] * membW[f * 128 + t];
  } else {
    int d = t - 128;
    acc = tprojB[d];
    for (int j = 0; j < 32; j++) acc += te[j] * tprojW[j * 128 + d];
  }
  h[(size_t)token * DMOD + t] = acc;
}

// ---------------- generic fp32 SGEMM, 64x64 tile ----------------
__global__ __launch_bounds__(256) void sgemm_k(
    const float* __restrict__ A, const float* __restrict__ B,
    const float* __restrict__ bias, float* __restrict__ C,
    int M, int N, int K, int lda, int ldb, int ldc, int flags) {
  __shared__ float As[16][65];
  __shared__ float Bs[16][65];
  int bm = blockIdx.y * 64, bn = blockIdx.x * 64;
  int tid = threadIdx.x;
  int tx = tid & 15, ty = tid >> 4;
  float acc[4][4] = {};
  for (int k0 = 0; k0 < K; k0 += 16) {
    int m = tid >> 2;
    int kb = (tid & 3) * 4;
#pragma unroll
    for (int i = 0; i < 4; i++) {
      int kk = kb + i;
      float v = 0.f;
      if (bm + m < M && k0 + kk < K) v = A[(size_t)(bm + m) * lda + k0 + kk];
      As[kk][m] = v;
    }
    int kk2 = tid >> 4;
    int nb = (tid & 15) * 4;
#pragma unroll
    for (int i = 0; i < 4; i++) {
      int n = nb + i;
      float v = 0.f;
      if (k0 + kk2 < K && bn + n < N) v = B[(size_t)(k0 + kk2) * ldb + bn + n];
      Bs[kk2][n] = v;
    }
    __syncthreads();
#pragma unroll
    for (int kk = 0; kk < 16; kk++) {
      float a[4], bb[4];
#pragma unroll
      for (int i = 0; i < 4; i++) a[i] = As[kk][ty * 4 + i];
#pragma unroll
      for (int j2 = 0; j2 < 4; j2++) bb[j2] = Bs[kk][tx * 4 + j2];
#pragma unroll
      for (int i = 0; i < 4; i++)
#pragma unroll
        for (int j2 = 0; j2 < 4; j2++) acc[i][j2] += a[i] * bb[j2];
    }
    __syncthreads();
  }
#pragma unroll
  for (int i = 0; i < 4; i++) {
    int m = bm + ty * 4 + i;
    if (m >= M) continue;
#pragma unroll
    for (int j2 = 0; j2 < 4; j2++) {
      int n = bn + tx * 4 + j2;
      if (n >= N) continue;
      float v = acc[i][j2];
      if (bias) v += bias[n];
      if (flags & 1) v += C[(size_t)m * ldc + n];
      C[(size_t)m * ldc + n] = v;
    }
  }
}

// ---------------- FFN GLU (a * gelu_exact(g)) ----------------
__global__ __launch_bounds__(256) void glugelu_k(const float* __restrict__ big, float* __restrict__ out) {
  int i = blockIdx.x * 256 + threadIdx.x;
  if (i >= BL * DFF) return;
  int token = i / DFF, j = i - token * DFF;
  float a = big[(size_t)token * (2 * DFF) + j];
  float g = big[(size_t)token * (2 * DFF) + DFF + j];
  float ge = 0.5f * g * (1.f + erff(g * 0.70710678118654752f));
  out[i] = a * ge;
}

// ---------------- LayerNorm over 256, one block per token ----------------
__global__ __launch_bounds__(256) void ln_k(const float* __restrict__ x, const float* __restrict__ w,
                                            const float* __restrict__ b, float* __restrict__ out) {
  __shared__ float red[4];
  int token = blockIdx.x, t = threadIdx.x;
  float v = x[(size_t)token * DMOD + t];
  float s = v;
#pragma unroll
  for (int o = 32; o; o >>= 1) s += __shfl_down(s, o, 64);
  int lane = t & 63, wid = t >> 6;
  if (lane == 0) red[wid] = s;
  __syncthreads();
  float mu = (red[0] + red[1] + red[2] + red[3]) * (1.f / 256.f);
  float dv = v - mu;
  s = dv * dv;
#pragma unroll
  for (int o = 32; o; o >>= 1) s += __shfl_down(s, o, 64);
  __syncthreads();
  if (lane == 0) red[wid] = s;
  __syncthreads();
  float var = (red[0] + red[1] + red[2] + red[3]) * (1.f / 256.f);
  out[(size_t)token * DMOD + t] = dv * rsqrtf(var + 1e-5f) * w[t] + b[t];
}

// ---------------- depthwise causal conv4 + bias + silu ----------------
__global__ __launch_bounds__(256) void conv_k(const float* __restrict__ big, const float* __restrict__ cw,
                                              const float* __restrict__ cb, float* __restrict__ ucv) {
  int i = blockIdx.x * 256 + threadIdx.x; // BL*DIN
  int token = i >> 9, c = i & 511;
  int b = token >> 9, l = token & 511;
  float acc = cb[c];
#pragma unroll
  for (int k = 0; k < 4; k++) {
    int l2 = l - 3 + k;
    if (l2 >= 0) acc += big[((size_t)(b * LSEQ + l2)) * 1024 + c] * cw[c * 4 + k];
  }
  ucv[i] = siluf_(acc);
}

// ---------------- xproj: u(512) -> 48 per token ----------------
__global__ __launch_bounds__(64) void xproj_k(const float* __restrict__ u, const float* __restrict__ W,
                                              float* __restrict__ xd) {
  int token = blockIdx.x;
  __shared__ float us[512];
  for (int j = threadIdx.x; j < 512; j += 64) us[j] = u[(size_t)token * DIN + j];
  __syncthreads();
  int t = threadIdx.x;
  if (t < 48) {
    float acc = 0.f;
    for (int c = 0; c < 512; c++) acc += us[c] * W[c * 48 + t];
    xd[token * 48 + t] = acc;
  }
}

// ---------------- dtproj + softplus ----------------
__global__ __launch_bounds__(256) void dtproj_k(const float* __restrict__ xd, const float* __restrict__ W,
                                                const float* __restrict__ bias, float* __restrict__ dt) {
  int i = blockIdx.x * 256 + threadIdx.x; // BL*DIN
  int token = i >> 9, c = i & 511;
  float acc = bias[c];
  const float* xr = xd + (size_t)token * 48;
#pragma unroll
  for (int r = 0; r < 16; r++) acc += xr[r] * W[r * 512 + c];
  float sp = (acc > 20.f) ? acc : log1pf(__expf(acc));
  dt[i] = sp;
}

// ---------------- selective scan: 16 lanes per (b,d) channel ----------------
__global__ __launch_bounds__(256) void scan_k(const float* __restrict__ dt, const float* __restrict__ ucv,
                                              const float* __restrict__ xd, const float* __restrict__ zbuf,
                                              const float* __restrict__ A_log, const float* __restrict__ D_p,
                                              float* __restrict__ gout) {
  int tid = blockIdx.x * 256 + threadIdx.x;
  int lane16 = tid & 15;
  int ch = tid >> 4;          // b*512 + d
  int b = ch >> 9, d = ch & 511;
  float An = -__expf(A_log[d * 16 + lane16]);
  float Dd = D_p[d];
  float hst = 0.f;
  for (int t = 0; t < LSEQ; t++) {
    int token = b * LSEQ + t;
    float dtv = dt[(size_t)token * DIN + d];
    float uv = ucv[(size_t)token * DIN + d];
    float Bn = xd[token * 48 + 16 + lane16];
    float Cn = xd[token * 48 + 32 + lane16];
    hst = __expf(dtv * An) * hst + (dtv * uv) * Bn;
    float y = hst * Cn;
    y += __shfl_xor(y, 1, 64);
    y += __shfl_xor(y, 2, 64);
    y += __shfl_xor(y, 4, 64);
    y += __shfl_xor(y, 8, 64);
    if (lane16 == 0) {
      float z = zbuf[(size_t)token * 1024 + 512 + d];
      gout[(size_t)token * DIN + d] = (y + uv * Dd) * siluf_(z);
    }
  }
}

// ---------------- SwiGLU for mlp: silu(g1)*g2 ----------------
__global__ __launch_bounds__(256) void silumul_k(const float* __restrict__ big, float* __restrict__ out) {
  int i = blockIdx.x * 256 + threadIdx.x; // BL*256
  int token = i >> 8, j = i & 255;
  float g1 = big[(size_t)token * 512 + j];
  float g2 = big[(size_t)token * 512 + 256 + j];
  out[i] = siluf_(g1) * g2;
}

// ---------------- dueling heads, one block per batch row ----------------
__device__ __forceinline__ float bred512(float v, float* red) {
  int lane = threadIdx.x & 63, wid = threadIdx.x >> 6;
#pragma unroll
  for (int o = 32; o; o >>= 1) v += __shfl_down(v, o, 64);
  __syncthreads();
  if (lane == 0) red[wid] = v;
  __syncthreads();
  float s = 0.f;
#pragma unroll
  for (int k = 0; k < 8; k++) s += red[k];
  return s;
}

__global__ __launch_bounds__(512) void head_k(
    const float* __restrict__ h, const float* __restrict__ nfw, const float* __restrict__ nfb,
    const float* vW1, const float* vb1, const float* vl1w, const float* vl1b,
    const float* vW2, const float* vb2, const float* vl2w, const float* vl2b,
    const float* vW3, const float* vb3,
    const float* aW1, const float* ab1, const float* al1w, const float* al1b,
    const float* aW2, const float* ab2, const float* al2w, const float* al2b,
    const float* aW3, const float* ab3, float* __restrict__ q) {
  __shared__ float f[256], t1[512], t2[256], red[8], outs[8];
  int b = blockIdx.x, t = threadIdx.x;
  const float* hr = h + ((size_t)b * LSEQ + (LSEQ - 1)) * DMOD;
  float v = (t < 256) ? hr[t] : 0.f;
  float mu = bred512(v, red) * (1.f / 256.f);
  float dv = (t < 256) ? (v - mu) : 0.f;
  float var = bred512(dv * dv, red) * (1.f / 256.f);
  if (t < 256) f[t] = dv * rsqrtf(var + 1e-5f) * nfw[t] + nfb[t];
  __syncthreads();
  for (int p = 0; p < 2; p++) {
    const float* W1 = p ? aW1 : vW1; const float* b1 = p ? ab1 : vb1;
    const float* l1w = p ? al1w : vl1w; const float* l1b = p ? al1b : vl1b;
    const float* W2 = p ? aW2 : vW2; const float* b2 = p ? ab2 : vb2;
    const float* l2w = p ? al2w : vl2w; const float* l2b = p ? al2b : vl2b;
    const float* W3 = p ? aW3 : vW3; const float* b3 = p ? ab3 : vb3;
    float a1 = b1[t];
    for (int j = 0; j < 256; j++) a1 += f[j] * W1[j * 512 + t];
    mu = bred512(a1, red) * (1.f / 512.f);
    dv = a1 - mu;
    var = bred512(dv * dv, red) * (1.f / 512.f);
    t1[t] = fmaxf(dv * rsqrtf(var + 1e-5f) * l1w[t] + l1b[t], 0.f);
    __syncthreads();
    float a2 = 0.f;
    if (t < 256) { a2 = b2[t]; for (int j = 0; j < 512; j++) a2 += t1[j] * W2[j * 256 + t]; }
    mu = bred512((t < 256) ? a2 : 0.f, red) * (1.f / 256.f);
    dv = (t < 256) ? (a2 - mu) : 0.f;
    var = bred512(dv * dv, red) * (1.f / 256.f);
    if (t < 256) t2[t] = fmaxf(dv * rsqrtf(var + 1e-5f) * l2w[t] + l2b[t], 0.f);
    __syncthreads();
    int nout = p ? 5 : 1;
    if (t < nout) {
      float a3 = b3[t];
      for (int j = 0; j < 256; j++) a3 += t2[j] * W3[j * nout + t];
      if (p == 0) outs[6] = a3; else outs[t] = a3;
    }
    __syncthreads();
  }
  if (t == 0) outs[7] = (outs[0] + outs[1] + outs[2] + outs[3] + outs[4]) * 0.2f;
  __syncthreads();
  if (t < 5) q[b * 5 + t] = outs[6] + outs[t] - outs[7];
}

extern "C" void kernel_launch(void* const* d_in, const int* in_sizes, int n_in,
                              void* d_out, int out_size, void* d_ws, size_t ws_size,
                              hipStream_t stream) {
  const float* src = (const float*)d_in[0];
  const float* tau = (const float*)d_in[1];
  const float* dain_Wm = (const float*)d_in[2];
  const float* dain_Ws = (const float*)d_in[3];
  const float* dain_Wg = (const float*)d_in[4];
  const float* dain_bg = (const float*)d_in[5];
  const float* memb_W = (const float*)d_in[6];
  const float* memb_b = (const float*)d_in[7];
  const float* t_w0 = (const float*)d_in[8];
  const float* t_b0 = (const float*)d_in[9];
  const float* t_w = (const float*)d_in[10];
  const float* t_b = (const float*)d_in[11];
  const float* tproj_W = (const float*)d_in[12];
  const float* tproj_b = (const float*)d_in[13];
  const float* ffn_W1 = (const float*)d_in[14];
  const float* ffn_b1 = (const float*)d_in[15];
  const float* ffn_W2 = (const float*)d_in[16];
  const float* ffn_b2 = (const float*)d_in[17];
  const float* n1_w = (const float*)d_in[18];
  const float* n1_b = (const float*)d_in[19];
  const float* inproj_W = (const float*)d_in[20];
  const float* conv_w = (const float*)d_in[21];
  const float* conv_b = (const float*)d_in[22];
  const float* xproj_W = (const float*)d_in[23];
  const float* dtproj_W = (const float*)d_in[24];
  const float* dt_bias = (const float*)d_in[25];
  const float* A_log = (const float*)d_in[26];
  const float* D_p = (const float*)d_in[27];
  const float* outproj_W = (const float*)d_in[28];
  const float* n2_w = (const float*)d_in[29];
  const float* n2_b = (const float*)d_in[30];
  const float* mlp_W1 = (const float*)d_in[31];
  const float* mlp_W2 = (const float*)d_in[32];
  const float* nf_w = (const float*)d_in[33];
  const float* nf_b = (const float*)d_in[34];
  const float* vW1 = (const float*)d_in[35]; const float* vb1 = (const float*)d_in[36];
  const float* vl1w = (const float*)d_in[37]; const float* vl1b = (const float*)d_in[38];
  const float* vW2 = (const float*)d_in[39]; const float* vb2 = (const float*)d_in[40];
  const float* vl2w = (const float*)d_in[41]; const float* vl2b = (const float*)d_in[42];
  const float* vW3 = (const float*)d_in[43]; const float* vb3 = (const float*)d_in[44];
  const float* aW1 = (const float*)d_in[45]; const float* ab1 = (const float*)d_in[46];
  const float* al1w = (const float*)d_in[47]; const float* al1b = (const float*)d_in[48];
  const float* aW2 = (const float*)d_in[49]; const float* ab2 = (const float*)d_in[50];
  const float* al2w = (const float*)d_in[51]; const float* al2b = (const float*)d_in[52];
  const float* aW3 = (const float*)d_in[53]; const float* ab3 = (const float*)d_in[54];
  float* out = (float*)d_out;

  float* ws = (float*)d_ws;
  float* stats = ws;                    // 256
  float* h   = stats + 256;             // BL*256
  float* hn  = h + (size_t)BL * DMOD;   // BL*256
  float* big = hn + (size_t)BL * DMOD;  // BL*1408 (ffn1 out 1364 / inproj out 1024 / mlp1 out 512)
  float* mid = big + (size_t)BL * 1408; // BL*682
  float* ucv = mid + (size_t)BL * DFF;  // BL*512
  float* xd  = ucv + (size_t)BL * DIN;  // BL*48
  float* dt  = xd + (size_t)BL * 48;    // BL*512
  float* gout = dt + (size_t)BL * DIN;  // BL*512

  dain_k<<<1, 1024, 0, stream>>>(src, dain_Wm, dain_Ws, dain_Wg, dain_bg, stats);
  embed_k<<<BL, 256, 0, stream>>>(src, tau, stats, memb_W, memb_b, t_w0, t_b0, t_w, t_b, tproj_W, tproj_b, h);
  sgemm_k<<<dim3(22, 32), 256, 0, stream>>>(h, ffn_W1, ffn_b1, big, BL, 2 * DFF, DMOD, DMOD, 2 * DFF, 2 * DFF, 0);
  glugelu_k<<<(BL * DFF + 255) / 256, 256, 0, stream>>>(big, mid);
  sgemm_k<<<dim3(4, 32), 256, 0, stream>>>(mid, ffn_W2, ffn_b2, h, BL, DMOD, DFF, DFF, DMOD, DMOD, 0);

  for (int i = 0; i < 8; i++) {
    ln_k<<<BL, 256, 0, stream>>>(h, n1_w + i * 256, n1_b + i * 256, hn);
    sgemm_k<<<dim3(16, 32), 256, 0, stream>>>(hn, inproj_W + (size_t)i * 256 * 1024, nullptr, big,
                                              BL, 1024, 256, 256, 1024, 1024, 0);
    conv_k<<<BL * DIN / 256, 256, 0, stream>>>(big, conv_w + (size_t)i * 512 * 4, conv_b + i * 512, ucv);
    xproj_k<<<BL, 64, 0, stream>>>(ucv, xproj_W + (size_t)i * 512 * 48, xd);
    dtproj_k<<<BL * DIN / 256, 256, 0, stream>>>(xd, dtproj_W + (size_t)i * 16 * 512, dt_bias + i * 512, dt);
    scan_k<<<BL * NST / 256, 256, 0, stream>>>(dt, ucv, xd, big, A_log + (size_t)i * 512 * 16, D_p + i * 512, gout);
    sgemm_k<<<dim3(4, 32), 256, 0, stream>>>(gout, outproj_W + (size_t)i * 512 * 256, nullptr, h,
                                             BL, 256, 512, 512, 256, 256, 1);
    ln_k<<<BL, 256, 0, stream>>>(h, n2_w + i * 256, n2_b + i * 256, hn);
    sgemm_k<<<dim3(8, 32), 256, 0, stream>>>(hn, mlp_W1 + (size_t)i * 256 * 512, nullptr, big,
                                             BL, 512, 256, 256, 512, 512, 0);
    silumul_k<<<BL, 256, 0, stream>>>(big, mid);
    sgemm_k<<<dim3(4, 32), 256, 0, stream>>>(mid, mlp_W2 + (size_t)i * 256 * 256, nullptr, h,
                                             BL, 256, 256, 256, 256, 256, 1);
  }

  head_k<<<NB, 512, 0, stream>>>(h, nf_w, nf_b,
                                 vW1, vb1, vl1w, vl1b, vW2, vb2, vl2w, vl2b, vW3, vb3,
                                 aW1, ab1, al1w, al1b, aW2, ab2, al2w, al2b, aW3, ab3, out);
  (void)in_sizes; (void)n_in; (void)out_size; (void)ws_size;
}

// Round 2
// 2568.220 us; speedup vs baseline: 1.9536x; 1.9536x over previous
//
#include <hip/hip_runtime.h>
#include <math.h>

// Model constants
#define BL   2048   // B*L = 4*512
#define LSEQ 512
#define NB   4
#define DMOD 256
#define DIN  512
#define NST  16
#define DFF  682
#define CHUNK 32
#define NCHK  16   // LSEQ / CHUNK
#define NCH   (NB * DIN)   // 2048 channels

__device__ __forceinline__ float sigmoidf_(float x) { return 1.f / (1.f + __expf(-x)); }
__device__ __forceinline__ float siluf_(float x) { return x / (1.f + __expf(-x)); }

// ---------------- DAIN stats (single block) ----------------
__global__ __launch_bounds__(1024) void dain_k(
    const float* __restrict__ src, const float* __restrict__ Wm,
    const float* __restrict__ Ws, const float* __restrict__ Wg,
    const float* __restrict__ bg, float* __restrict__ stats) {
  __shared__ float part[1024];
  __shared__ float avg_s[128], sub_s[128], std_s[128], mn_s[128], inv_s[128];
  int tid = threadIdx.x;
  int p = tid >> 3, j = tid & 7;
  int b = p >> 5, f = p & 31;
  float s = 0.f;
  for (int l = j * 64; l < j * 64 + 64; ++l) s += src[((size_t)b * LSEQ + l) * 32 + f];
  part[tid] = s;
  __syncthreads();
  if (tid < 128) { float a = 0; for (int k = 0; k < 8; k++) a += part[tid * 8 + k]; avg_s[tid] = a * (1.f / 512.f); }
  __syncthreads();
  if (tid < 128) {
    int bb = tid >> 5, ff = tid & 31;
    float a = 0; for (int g = 0; g < 32; g++) a += avg_s[bb * 32 + g] * Wm[ff * 32 + g];
    sub_s[tid] = a;
  }
  __syncthreads();
  float sub = sub_s[p];
  s = 0.f;
  for (int l = j * 64; l < j * 64 + 64; ++l) {
    float v = src[((size_t)b * LSEQ + l) * 32 + f] - sub; s += v * v;
  }
  part[tid] = s;
  __syncthreads();
  if (tid < 128) { float a = 0; for (int k = 0; k < 8; k++) a += part[tid * 8 + k]; std_s[tid] = sqrtf(a * (1.f / 512.f)); }
  __syncthreads();
  if (tid < 128) {
    int bb = tid >> 5, ff = tid & 31;
    float a = 0; for (int g = 0; g < 32; g++) a += std_s[bb * 32 + g] * Ws[ff * 32 + g];
    if (a <= 1e-8f) a = 1.f;
    inv_s[tid] = 1.f / a;
    mn_s[tid] = (avg_s[tid] - sub_s[tid]) / a;
  }
  __syncthreads();
  if (tid < 128) {
    int bb = tid >> 5, ff = tid & 31;
    float a = bg[ff]; for (int g = 0; g < 32; g++) a += mn_s[bb * 32 + g] * Wg[ff * 32 + g];
    float gate = sigmoidf_(a);
    float scl = gate * inv_s[tid];
    stats[tid] = scl;
    stats[128 + tid] = sub_s[tid] * scl;
  }
}

// ---------------- embed: market + tproj -> h ----------------
__global__ __launch_bounds__(256) void embed_k(
    const float* __restrict__ src, const float* __restrict__ tau,
    const float* __restrict__ stats, const float* __restrict__ membW,
    const float* __restrict__ membB, const float* __restrict__ tw0,
    const float* __restrict__ tb0, const float* __restrict__ tw,
    const float* __restrict__ tb, const float* __restrict__ tprojW,
    const float* __restrict__ tprojB, float* __restrict__ h) {
  int token = blockIdx.x;
  int b = token >> 9;
  int t = threadIdx.x;
  __shared__ float xs[32], te[32];
  if (t < 32) {
    float scl = stats[b * 32 + t], shf = stats[128 + b * 32 + t];
    xs[t] = src[(size_t)token * 32 + t] * scl - shf;
  } else if (t < 64) {
    int j = t - 32;
    const float* tr = tau + (size_t)token * 8;
    float a;
    if (j < 31) { a = tb[j]; for (int k = 0; k < 8; k++) a += tr[k] * tw[k * 31 + j]; a = sinf(a); }
    else        { a = tb0[0]; for (int k = 0; k < 8; k++) a += tr[k] * tw0[k]; }
    te[j] = a;
  }
  __syncthreads();
  float acc;
  if (t < 128) {
    acc = membB[t];
    for (int f = 0; f < 32; f++) acc += xs[f] * membW[f * 128 + t];
  } else {
    int d = t - 128;
    acc = tprojB[d];
    for (int j = 0; j < 32; j++) acc += te[j] * tprojW[j * 128 + d];
  }
  h[(size_t)token * DMOD + t] = acc;
}

// ---------------- generic fp32 SGEMM, 64x64 tile ----------------
__global__ __launch_bounds__(256) void sgemm_k(
    const float* __restrict__ A, const float* __restrict__ B,
    const float* __restrict__ bias, float* __restrict__ C,
    int M, int N, int K, int lda, int ldb, int ldc, int flags) {
  __shared__ float As[16][65];
  __shared__ float Bs[16][65];
  int bm = blockIdx.y * 64, bn = blockIdx.x * 64;
  int tid = threadIdx.x;
  int tx = tid & 15, ty = tid >> 4;
  float acc[4][4] = {};
  for (int k0 = 0; k0 < K; k0 += 16) {
    int m = tid >> 2;
    int kb = (tid & 3) * 4;
#pragma unroll
    for (int i = 0; i < 4; i++) {
      int kk = kb + i;
      float v = 0.f;
      if (bm + m < M && k0 + kk < K) v = A[(size_t)(bm + m) * lda + k0 + kk];
      As[kk][m] = v;
    }
    int kk2 = tid >> 4;
    int nb = (tid & 15) * 4;
#pragma unroll
    for (int i = 0; i < 4; i++) {
      int n = nb + i;
      float v = 0.f;
      if (k0 + kk2 < K && bn + n < N) v = B[(size_t)(k0 + kk2) * ldb + bn + n];
      Bs[kk2][n] = v;
    }
    __syncthreads();
#pragma unroll
    for (int kk = 0; kk < 16; kk++) {
      float a[4], bb[4];
#pragma unroll
      for (int i = 0; i < 4; i++) a[i] = As[kk][ty * 4 + i];
#pragma unroll
      for (int j2 = 0; j2 < 4; j2++) bb[j2] = Bs[kk][tx * 4 + j2];
#pragma unroll
      for (int i = 0; i < 4; i++)
#pragma unroll
        for (int j2 = 0; j2 < 4; j2++) acc[i][j2] += a[i] * bb[j2];
    }
    __syncthreads();
  }
#pragma unroll
  for (int i = 0; i < 4; i++) {
    int m = bm + ty * 4 + i;
    if (m >= M) continue;
#pragma unroll
    for (int j2 = 0; j2 < 4; j2++) {
      int n = bn + tx * 4 + j2;
      if (n >= N) continue;
      float v = acc[i][j2];
      if (bias) v += bias[n];
      if (flags & 1) v += C[(size_t)m * ldc + n];
      C[(size_t)m * ldc + n] = v;
    }
  }
}

// ---------------- FFN GLU (a * gelu_exact(g)) ----------------
__global__ __launch_bounds__(256) void glugelu_k(const float* __restrict__ big, float* __restrict__ out) {
  int i = blockIdx.x * 256 + threadIdx.x;
  if (i >= BL * DFF) return;
  int token = i / DFF, j = i - token * DFF;
  float a = big[(size_t)token * (2 * DFF) + j];
  float g = big[(size_t)token * (2 * DFF) + DFF + j];
  float ge = 0.5f * g * (1.f + erff(g * 0.70710678118654752f));
  out[i] = a * ge;
}

// ---------------- LayerNorm over 256, one block per token ----------------
__global__ __launch_bounds__(256) void ln_k(const float* __restrict__ x, const float* __restrict__ w,
                                            const float* __restrict__ b, float* __restrict__ out) {
  __shared__ float red[4];
  int token = blockIdx.x, t = threadIdx.x;
  float v = x[(size_t)token * DMOD + t];
  float s = v;
#pragma unroll
  for (int o = 32; o; o >>= 1) s += __shfl_down(s, o, 64);
  int lane = t & 63, wid = t >> 6;
  if (lane == 0) red[wid] = s;
  __syncthreads();
  float mu = (red[0] + red[1] + red[2] + red[3]) * (1.f / 256.f);
  float dv = v - mu;
  s = dv * dv;
#pragma unroll
  for (int o = 32; o; o >>= 1) s += __shfl_down(s, o, 64);
  __syncthreads();
  if (lane == 0) red[wid] = s;
  __syncthreads();
  float var = (red[0] + red[1] + red[2] + red[3]) * (1.f / 256.f);
  out[(size_t)token * DMOD + t] = dv * rsqrtf(var + 1e-5f) * w[t] + b[t];
}

// ---------------- depthwise causal conv4 + bias + silu ----------------
__global__ __launch_bounds__(256) void conv_k(const float* __restrict__ big, const float* __restrict__ cw,
                                              const float* __restrict__ cb, float* __restrict__ ucv) {
  int i = blockIdx.x * 256 + threadIdx.x; // BL*DIN
  int token = i >> 9, c = i & 511;
  int b = token >> 9, l = token & 511;
  float acc = cb[c];
#pragma unroll
  for (int k = 0; k < 4; k++) {
    int l2 = l - 3 + k;
    if (l2 >= 0) acc += big[((size_t)(b * LSEQ + l2)) * 1024 + c] * cw[c * 4 + k];
  }
  ucv[i] = siluf_(acc);
}

// ---------------- xproj: u(512) -> 48 per token ----------------
__global__ __launch_bounds__(64) void xproj_k(const float* __restrict__ u, const float* __restrict__ W,
                                              float* __restrict__ xd) {
  int token = blockIdx.x;
  __shared__ float us[512];
  for (int j = threadIdx.x; j < 512; j += 64) us[j] = u[(size_t)token * DIN + j];
  __syncthreads();
  int t = threadIdx.x;
  if (t < 48) {
    float acc = 0.f;
    for (int c = 0; c < 512; c++) acc += us[c] * W[c * 48 + t];
    xd[token * 48 + t] = acc;
  }
}

// ---------------- dtproj + softplus ----------------
__global__ __launch_bounds__(256) void dtproj_k(const float* __restrict__ xd, const float* __restrict__ W,
                                                const float* __restrict__ bias, float* __restrict__ dt) {
  int i = blockIdx.x * 256 + threadIdx.x; // BL*DIN
  int token = i >> 9, c = i & 511;
  float acc = bias[c];
  const float* xr = xd + (size_t)token * 48;
#pragma unroll
  for (int r = 0; r < 16; r++) acc += xr[r] * W[r * 512 + c];
  float sp = (acc > 20.f) ? acc : log1pf(__expf(acc));
  dt[i] = sp;
}

// ---------------- chunked parallel scan ----------------
// thread id -> lane n = tid&15, chunk c = (tid>>4)&15, channel ch = tid>>8
// Phase A: per-chunk local scan with h0 = 0; record P = prod(dA), H = local end state.
__global__ __launch_bounds__(256) void scanA_k(const float* __restrict__ dt, const float* __restrict__ ucv,
                                               const float* __restrict__ xd, const float* __restrict__ A_log,
                                               float* __restrict__ Pbuf, float* __restrict__ Hbuf) {
  int tid = blockIdx.x * 256 + threadIdx.x;
  int n = tid & 15;
  int c = (tid >> 4) & (NCHK - 1);
  int ch = tid >> 8;            // b*512 + d
  int b = ch >> 9, d = ch & 511;
  float An = -__expf(A_log[d * 16 + n]);
  float P = 1.f, h = 0.f;
  int t0 = b * LSEQ + c * CHUNK;
  for (int t = 0; t < CHUNK; t++) {
    int token = t0 + t;
    float dtv = dt[(size_t)token * DIN + d];
    float uv = ucv[(size_t)token * DIN + d];
    float Bn = xd[token * 48 + 16 + n];
    float dA = __expf(dtv * An);
    P *= dA;
    h = dA * h + (dtv * uv) * Bn;
  }
  Pbuf[tid] = P;
  Hbuf[tid] = h;
}

// Phase B: sequential composition over the 16 chunk boundaries per (channel, state).
__global__ __launch_bounds__(256) void scanB_k(const float* __restrict__ Pbuf, const float* __restrict__ Hbuf,
                                               float* __restrict__ Hin) {
  int tid = blockIdx.x * 256 + threadIdx.x;  // [ch][lane]
  int n = tid & 15;
  int ch = tid >> 4;
  float h = 0.f;
#pragma unroll
  for (int c = 0; c < NCHK; c++) {
    int idx = ch * (NCHK * 16) + c * 16 + n;
    Hin[idx] = h;
    h = Pbuf[idx] * h + Hbuf[idx];
  }
}

// Phase C: redo chunk scan with correct initial state, emit gated output.
__global__ __launch_bounds__(256) void scanC_k(const float* __restrict__ dt, const float* __restrict__ ucv,
                                               const float* __restrict__ xd, const float* __restrict__ zbuf,
                                               const float* __restrict__ A_log, const float* __restrict__ D_p,
                                               const float* __restrict__ Hin, float* __restrict__ gout) {
  int tid = blockIdx.x * 256 + threadIdx.x;
  int n = tid & 15;
  int c = (tid >> 4) & (NCHK - 1);
  int ch = tid >> 8;
  int b = ch >> 9, d = ch & 511;
  float An = -__expf(A_log[d * 16 + n]);
  float Dd = D_p[d];
  float h = Hin[tid];
  int t0 = b * LSEQ + c * CHUNK;
  for (int t = 0; t < CHUNK; t++) {
    int token = t0 + t;
    float dtv = dt[(size_t)token * DIN + d];
    float uv = ucv[(size_t)token * DIN + d];
    float Bn = xd[token * 48 + 16 + n];
    float Cn = xd[token * 48 + 32 + n];
    float dA = __expf(dtv * An);
    h = dA * h + (dtv * uv) * Bn;
    float y = h * Cn;
    y += __shfl_xor(y, 1, 64);
    y += __shfl_xor(y, 2, 64);
    y += __shfl_xor(y, 4, 64);
    y += __shfl_xor(y, 8, 64);
    if (n == 0) {
      float z = zbuf[(size_t)token * 1024 + 512 + d];
      gout[(size_t)token * DIN + d] = (y + uv * Dd) * siluf_(z);
    }
  }
}

// ---------------- SwiGLU for mlp: silu(g1)*g2 ----------------
__global__ __launch_bounds__(256) void silumul_k(const float* __restrict__ big, float* __restrict__ out) {
  int i = blockIdx.x * 256 + threadIdx.x; // BL*256
  int token = i >> 8, j = i & 255;
  float g1 = big[(size_t)token * 512 + j];
  float g2 = big[(size_t)token * 512 + 256 + j];
  out[i] = siluf_(g1) * g2;
}

// ---------------- dueling heads, one block per batch row ----------------
__device__ __forceinline__ float bred512(float v, float* red) {
  int lane = threadIdx.x & 63, wid = threadIdx.x >> 6;
#pragma unroll
  for (int o = 32; o; o >>= 1) v += __shfl_down(v, o, 64);
  __syncthreads();
  if (lane == 0) red[wid] = v;
  __syncthreads();
  float s = 0.f;
#pragma unroll
  for (int k = 0; k < 8; k++) s += red[k];
  return s;
}

__global__ __launch_bounds__(512) void head_k(
    const float* __restrict__ h, const float* __restrict__ nfw, const float* __restrict__ nfb,
    const float* vW1, const float* vb1, const float* vl1w, const float* vl1b,
    const float* vW2, const float* vb2, const float* vl2w, const float* vl2b,
    const float* vW3, const float* vb3,
    const float* aW1, const float* ab1, const float* al1w, const float* al1b,
    const float* aW2, const float* ab2, const float* al2w, const float* al2b,
    const float* aW3, const float* ab3, float* __restrict__ q) {
  __shared__ float f[256], t1[512], t2[256], red[8], outs[8];
  int b = blockIdx.x, t = threadIdx.x;
  const float* hr = h + ((size_t)b * LSEQ + (LSEQ - 1)) * DMOD;
  float v = (t < 256) ? hr[t] : 0.f;
  float mu = bred512(v, red) * (1.f / 256.f);
  float dv = (t < 256) ? (v - mu) : 0.f;
  float var = bred512(dv * dv, red) * (1.f / 256.f);
  if (t < 256) f[t] = dv * rsqrtf(var + 1e-5f) * nfw[t] + nfb[t];
  __syncthreads();
  for (int p = 0; p < 2; p++) {
    const float* W1 = p ? aW1 : vW1; const float* b1 = p ? ab1 : vb1;
    const float* l1w = p ? al1w : vl1w; const float* l1b = p ? al1b : vl1b;
    const float* W2 = p ? aW2 : vW2; const float* b2 = p ? ab2 : vb2;
    const float* l2w = p ? al2w : vl2w; const float* l2b = p ? al2b : vl2b;
    const float* W3 = p ? aW3 : vW3; const float* b3 = p ? ab3 : vb3;
    float a1 = b1[t];
    for (int j = 0; j < 256; j++) a1 += f[j] * W1[j * 512 + t];
    mu = bred512(a1, red) * (1.f / 512.f);
    dv = a1 - mu;
    var = bred512(dv * dv, red) * (1.f / 512.f);
    t1[t] = fmaxf(dv * rsqrtf(var + 1e-5f) * l1w[t] + l1b[t], 0.f);
    __syncthreads();
    float a2 = 0.f;
    if (t < 256) { a2 = b2[t]; for (int j = 0; j < 512; j++) a2 += t1[j] * W2[j * 256 + t]; }
    mu = bred512((t < 256) ? a2 : 0.f, red) * (1.f / 256.f);
    dv = (t < 256) ? (a2 - mu) : 0.f;
    var = bred512(dv * dv, red) * (1.f / 256.f);
    if (t < 256) t2[t] = fmaxf(dv * rsqrtf(var + 1e-5f) * l2w[t] + l2b[t], 0.f);
    __syncthreads();
    int nout = p ? 5 : 1;
    if (t < nout) {
      float a3 = b3[t];
      for (int j = 0; j < 256; j++) a3 += t2[j] * W3[j * nout + t];
      if (p == 0) outs[6] = a3; else outs[t] = a3;
    }
    __syncthreads();
  }
  if (t == 0) outs[7] = (outs[0] + outs[1] + outs[2] + outs[3] + outs[4]) * 0.2f;
  __syncthreads();
  if (t < 5) q[b * 5 + t] = outs[6] + outs[t] - outs[7];
}

extern "C" void kernel_launch(void* const* d_in, const int* in_sizes, int n_in,
                              void* d_out, int out_size, void* d_ws, size_t ws_size,
                              hipStream_t stream) {
  const float* src = (const float*)d_in[0];
  const float* tau = (const float*)d_in[1];
  const float* dain_Wm = (const float*)d_in[2];
  const float* dain_Ws = (const float*)d_in[3];
  const float* dain_Wg = (const float*)d_in[4];
  const float* dain_bg = (const float*)d_in[5];
  const float* memb_W = (const float*)d_in[6];
  const float* memb_b = (const float*)d_in[7];
  const float* t_w0 = (const float*)d_in[8];
  const float* t_b0 = (const float*)d_in[9];
  const float* t_w = (const float*)d_in[10];
  const float* t_b = (const float*)d_in[11];
  const float* tproj_W = (const float*)d_in[12];
  const float* tproj_b = (const float*)d_in[13];
  const float* ffn_W1 = (const float*)d_in[14];
  const float* ffn_b1 = (const float*)d_in[15];
  const float* ffn_W2 = (const float*)d_in[16];
  const float* ffn_b2 = (const float*)d_in[17];
  const float* n1_w = (const float*)d_in[18];
  const float* n1_b = (const float*)d_in[19];
  const float* inproj_W = (const float*)d_in[20];
  const float* conv_w = (const float*)d_in[21];
  const float* conv_b = (const float*)d_in[22];
  const float* xproj_W = (const float*)d_in[23];
  const float* dtproj_W = (const float*)d_in[24];
  const float* dt_bias = (const float*)d_in[25];
  const float* A_log = (const float*)d_in[26];
  const float* D_p = (const float*)d_in[27];
  const float* outproj_W = (const float*)d_in[28];
  const float* n2_w = (const float*)d_in[29];
  const float* n2_b = (const float*)d_in[30];
  const float* mlp_W1 = (const float*)d_in[31];
  const float* mlp_W2 = (const float*)d_in[32];
  const float* nf_w = (const float*)d_in[33];
  const float* nf_b = (const float*)d_in[34];
  const float* vW1 = (const float*)d_in[35]; const float* vb1 = (const float*)d_in[36];
  const float* vl1w = (const float*)d_in[37]; const float* vl1b = (const float*)d_in[38];
  const float* vW2 = (const float*)d_in[39]; const float* vb2 = (const float*)d_in[40];
  const float* vl2w = (const float*)d_in[41]; const float* vl2b = (const float*)d_in[42];
  const float* vW3 = (const float*)d_in[43]; const float* vb3 = (const float*)d_in[44];
  const float* aW1 = (const float*)d_in[45]; const float* ab1 = (const float*)d_in[46];
  const float* al1w = (const float*)d_in[47]; const float* al1b = (const float*)d_in[48];
  const float* aW2 = (const float*)d_in[49]; const float* ab2 = (const float*)d_in[50];
  const float* al2w = (const float*)d_in[51]; const float* al2b = (const float*)d_in[52];
  const float* aW3 = (const float*)d_in[53]; const float* ab3 = (const float*)d_in[54];
  float* out = (float*)d_out;

  float* ws = (float*)d_ws;
  float* stats = ws;                    // 256
  float* h   = stats + 256;             // BL*256
  float* hn  = h + (size_t)BL * DMOD;   // BL*256
  float* big = hn + (size_t)BL * DMOD;  // BL*1408
  float* mid = big + (size_t)BL * 1408; // BL*682
  float* ucv = mid + (size_t)BL * DFF;  // BL*512
  float* xd  = ucv + (size_t)BL * DIN;  // BL*48
  float* dt  = xd + (size_t)BL * 48;    // BL*512
  float* gout = dt + (size_t)BL * DIN;  // BL*512
  float* Pbuf = gout + (size_t)BL * DIN;       // NCH*NCHK*16 = 524288
  float* Hbuf = Pbuf + (size_t)NCH * NCHK * 16;
  float* Hin  = Hbuf + (size_t)NCH * NCHK * 16;

  dain_k<<<1, 1024, 0, stream>>>(src, dain_Wm, dain_Ws, dain_Wg, dain_bg, stats);
  embed_k<<<BL, 256, 0, stream>>>(src, tau, stats, memb_W, memb_b, t_w0, t_b0, t_w, t_b, tproj_W, tproj_b, h);
  sgemm_k<<<dim3(22, 32), 256, 0, stream>>>(h, ffn_W1, ffn_b1, big, BL, 2 * DFF, DMOD, DMOD, 2 * DFF, 2 * DFF, 0);
  glugelu_k<<<(BL * DFF + 255) / 256, 256, 0, stream>>>(big, mid);
  sgemm_k<<<dim3(4, 32), 256, 0, stream>>>(mid, ffn_W2, ffn_b2, h, BL, DMOD, DFF, DFF, DMOD, DMOD, 0);

  const int scanAC_blocks = NCH * NCHK * 16 / 256; // 2048
  for (int i = 0; i < 8; i++) {
    ln_k<<<BL, 256, 0, stream>>>(h, n1_w + i * 256, n1_b + i * 256, hn);
    sgemm_k<<<dim3(16, 32), 256, 0, stream>>>(hn, inproj_W + (size_t)i * 256 * 1024, nullptr, big,
                                              BL, 1024, 256, 256, 1024, 1024, 0);
    conv_k<<<BL * DIN / 256, 256, 0, stream>>>(big, conv_w + (size_t)i * 512 * 4, conv_b + i * 512, ucv);
    xproj_k<<<BL, 64, 0, stream>>>(ucv, xproj_W + (size_t)i * 512 * 48, xd);
    dtproj_k<<<BL * DIN / 256, 256, 0, stream>>>(xd, dtproj_W + (size_t)i * 16 * 512, dt_bias + i * 512, dt);
    scanA_k<<<scanAC_blocks, 256, 0, stream>>>(dt, ucv, xd, A_log + (size_t)i * 512 * 16, Pbuf, Hbuf);
    scanB_k<<<NCH * 16 / 256, 256, 0, stream>>>(Pbuf, Hbuf, Hin);
    scanC_k<<<scanAC_blocks, 256, 0, stream>>>(dt, ucv, xd, big, A_log + (size_t)i * 512 * 16,
                                               D_p + i * 512, Hin, gout);
    sgemm_k<<<dim3(4, 32), 256, 0, stream>>>(gout, outproj_W + (size_t)i * 512 * 256, nullptr, h,
                                             BL, 256, 512, 512, 256, 256, 1);
    ln_k<<<BL, 256, 0, stream>>>(h, n2_w + i * 256, n2_b + i * 256, hn);
    sgemm_k<<<dim3(8, 32), 256, 0, stream>>>(hn, mlp_W1 + (size_t)i * 256 * 512, nullptr, big,
                                             BL, 512, 256, 256, 512, 512, 0);
    silumul_k<<<BL, 256, 0, stream>>>(big, mid);
    sgemm_k<<<dim3(4, 32), 256, 0, stream>>>(mid, mlp_W2 + (size_t)i * 256 * 256, nullptr, h,
                                             BL, 256, 256, 256, 256, 256, 1);
  }

  head_k<<<NB, 512, 0, stream>>>(h, nf_w, nf_b,
                                 vW1, vb1, vl1w, vl1b, vW2, vb2, vl2w, vl2b, vW3, vb3,
                                 aW1, ab1, al1w, al1b, aW2, ab2, al2w, al2b, aW3, ab3, out);
  (void)in_sizes; (void)n_in; (void)out_size; (void)ws_size;
}

// Round 4
// 1277.929 us; speedup vs baseline: 3.9261x; 2.0097x over previous
//
#include <hip/hip_runtime.h>
#include <math.h>

// Model constants
#define BL   2048   // B*L = 4*512
#define LSEQ 512
#define NB   4
#define DMOD 256
#define DIN  512
#define NST  16
#define DFF  682
#define CHUNK 32
#define NCHK  16
#define NCH   (NB * DIN)

typedef __attribute__((ext_vector_type(4))) float f32x4;
typedef __attribute__((ext_vector_type(8))) _Float16 f16x8;

__device__ __forceinline__ float sigmoidf_(float x) { return 1.f / (1.f + __expf(-x)); }
__device__ __forceinline__ float siluf_(float x) { return x / (1.f + __expf(-x)); }

// ---------------- DAIN stats (single block) ----------------
__global__ __launch_bounds__(1024) void dain_k(
    const float* __restrict__ src, const float* __restrict__ Wm,
    const float* __restrict__ Ws, const float* __restrict__ Wg,
    const float* __restrict__ bg, float* __restrict__ stats) {
  __shared__ float part[1024];
  __shared__ float avg_s[128], sub_s[128], std_s[128], mn_s[128], inv_s[128];
  int tid = threadIdx.x;
  int p = tid >> 3, j = tid & 7;
  int b = p >> 5, f = p & 31;
  float s = 0.f;
  for (int l = j * 64; l < j * 64 + 64; ++l) s += src[((size_t)b * LSEQ + l) * 32 + f];
  part[tid] = s;
  __syncthreads();
  if (tid < 128) { float a = 0; for (int k = 0; k < 8; k++) a += part[tid * 8 + k]; avg_s[tid] = a * (1.f / 512.f); }
  __syncthreads();
  if (tid < 128) {
    int bb = tid >> 5, ff = tid & 31;
    float a = 0; for (int g = 0; g < 32; g++) a += avg_s[bb * 32 + g] * Wm[ff * 32 + g];
    sub_s[tid] = a;
  }
  __syncthreads();
  float sub = sub_s[p];
  s = 0.f;
  for (int l = j * 64; l < j * 64 + 64; ++l) {
    float v = src[((size_t)b * LSEQ + l) * 32 + f] - sub; s += v * v;
  }
  part[tid] = s;
  __syncthreads();
  if (tid < 128) { float a = 0; for (int k = 0; k < 8; k++) a += part[tid * 8 + k]; std_s[tid] = sqrtf(a * (1.f / 512.f)); }
  __syncthreads();
  if (tid < 128) {
    int bb = tid >> 5, ff = tid & 31;
    float a = 0; for (int g = 0; g < 32; g++) a += std_s[bb * 32 + g] * Ws[ff * 32 + g];
    if (a <= 1e-8f) a = 1.f;
    inv_s[tid] = 1.f / a;
    mn_s[tid] = (avg_s[tid] - sub_s[tid]) / a;
  }
  __syncthreads();
  if (tid < 128) {
    int bb = tid >> 5, ff = tid & 31;
    float a = bg[ff]; for (int g = 0; g < 32; g++) a += mn_s[bb * 32 + g] * Wg[ff * 32 + g];
    float gate = sigmoidf_(a);
    float scl = gate * inv_s[tid];
    stats[tid] = scl;
    stats[128 + tid] = sub_s[tid] * scl;
  }
}

// ---------------- embed: market + tproj -> h (fp32 + f16) ----------------
__global__ __launch_bounds__(256) void embed_k(
    const float* __restrict__ src, const float* __restrict__ tau,
    const float* __restrict__ stats, const float* __restrict__ membW,
    const float* __restrict__ membB, const float* __restrict__ tw0,
    const float* __restrict__ tb0, const float* __restrict__ tw,
    const float* __restrict__ tb, const float* __restrict__ tprojW,
    const float* __restrict__ tprojB, float* __restrict__ h,
    _Float16* __restrict__ h_hf) {
  int token = blockIdx.x;
  int b = token >> 9;
  int t = threadIdx.x;
  __shared__ float xs[32], te[32];
  if (t < 32) {
    float scl = stats[b * 32 + t], shf = stats[128 + b * 32 + t];
    xs[t] = src[(size_t)token * 32 + t] * scl - shf;
  } else if (t < 64) {
    int j = t - 32;
    const float* tr = tau + (size_t)token * 8;
    float a;
    if (j < 31) { a = tb[j]; for (int k = 0; k < 8; k++) a += tr[k] * tw[k * 31 + j]; a = sinf(a); }
    else        { a = tb0[0]; for (int k = 0; k < 8; k++) a += tr[k] * tw0[k]; }
    te[j] = a;
  }
  __syncthreads();
  float acc;
  if (t < 128) {
    acc = membB[t];
    for (int f = 0; f < 32; f++) acc += xs[f] * membW[f * 128 + t];
  } else {
    int d = t - 128;
    acc = tprojB[d];
    for (int j = 0; j < 32; j++) acc += te[j] * tprojW[j * 128 + d];
  }
  h[(size_t)token * DMOD + t] = acc;
  h_hf[(size_t)token * DMOD + t] = (_Float16)acc;
}

// ---------------- weight transpose-convert: fp32 [K][N] -> f16 [Nout][Kout] (padded zeros)
__global__ __launch_bounds__(256) void convT_k(const float* __restrict__ W, _Float16* __restrict__ WT,
                                               int K, int N, int Kout, int Nout) {
  int l = blockIdx.y;
  const float* Wl = W + (size_t)l * K * N;
  _Float16* WTl = WT + (size_t)l * Nout * Kout;
  int i = blockIdx.x * 256 + threadIdx.x;
  if (i >= Nout * Kout) return;
  int n = i / Kout, k = i - n * Kout;
  float v = (k < K && n < N) ? Wl[(size_t)k * N + n] : 0.f;
  WTl[i] = (_Float16)v;
}

// ---------------- f16 MFMA GEMM: C(MxN,f32) = A(MxK,f16) * WT^T (WT is [Npad][K] f16)
// grid: (Npad/64, M/64), 256 threads. flags&1: += existing C. bias optional (f32[N]).
__global__ __launch_bounds__(256) void gemm_hf_k(
    const _Float16* __restrict__ A, const _Float16* __restrict__ WT,
    const float* __restrict__ bias, float* __restrict__ C,
    int M, int Nstore, int K, int ldc, int flags) {
  __shared__ _Float16 As[64][40];
  __shared__ _Float16 Bs[64][40];
  int bm = blockIdx.y * 64, bn = blockIdx.x * 64;
  int t = threadIdx.x;
  int w = t >> 6, l = t & 63;
  int wm = w >> 1, wn = w & 1;
  int srow = t >> 2, sk = (t & 3) * 8;
  f32x4 acc[2][2] = {};
  int lr = l & 15, lk = (l >> 4) * 8;
  for (int k0 = 0; k0 < K; k0 += 32) {
    *(uint4*)&As[srow][sk] = *(const uint4*)&A[(size_t)(bm + srow) * K + k0 + sk];
    *(uint4*)&Bs[srow][sk] = *(const uint4*)&WT[(size_t)(bn + srow) * K + k0 + sk];
    __syncthreads();
    f16x8 a0 = *(const f16x8*)&As[wm * 32 + lr][lk];
    f16x8 a1 = *(const f16x8*)&As[wm * 32 + 16 + lr][lk];
    f16x8 b0 = *(const f16x8*)&Bs[wn * 32 + lr][lk];
    f16x8 b1 = *(const f16x8*)&Bs[wn * 32 + 16 + lr][lk];
    acc[0][0] = __builtin_amdgcn_mfma_f32_16x16x32_f16(a0, b0, acc[0][0], 0, 0, 0);
    acc[0][1] = __builtin_amdgcn_mfma_f32_16x16x32_f16(a0, b1, acc[0][1], 0, 0, 0);
    acc[1][0] = __builtin_amdgcn_mfma_f32_16x16x32_f16(a1, b0, acc[1][0], 0, 0, 0);
    acc[1][1] = __builtin_amdgcn_mfma_f32_16x16x32_f16(a1, b1, acc[1][1], 0, 0, 0);
    __syncthreads();
  }
  int lq = l >> 4;
#pragma unroll
  for (int i = 0; i < 2; i++) {
#pragma unroll
    for (int j = 0; j < 2; j++) {
      int col = bn + wn * 32 + j * 16 + lr;
      if (col >= Nstore) continue;
      float bv = bias ? bias[col] : 0.f;
#pragma unroll
      for (int r = 0; r < 4; r++) {
        int row = bm + wm * 32 + i * 16 + lq * 4 + r;
        float v = acc[i][j][r] + bv;
        size_t idx = (size_t)row * ldc + col;
        if (flags & 1) v += C[idx];
        C[idx] = v;
      }
    }
  }
}

// ---------------- FFN GLU (a * gelu_exact(g)) -> f16 padded to 704 ----------------
__global__ __launch_bounds__(256) void glugelu_k(const float* __restrict__ big, _Float16* __restrict__ out) {
  int i = blockIdx.x * 256 + threadIdx.x; // BL*704
  int token = i / 704, j = i - token * 704;
  float r = 0.f;
  if (j < DFF) {
    float a = big[(size_t)token * (2 * DFF) + j];
    float g = big[(size_t)token * (2 * DFF) + DFF + j];
    r = a * 0.5f * g * (1.f + erff(g * 0.70710678118654752f));
  }
  out[i] = (_Float16)r;
}

// ---------------- LayerNorm over 256 -> f16 out ----------------
__global__ __launch_bounds__(256) void ln_k(const float* __restrict__ x, const float* __restrict__ w,
                                            const float* __restrict__ b, _Float16* __restrict__ out) {
  __shared__ float red[4];
  int token = blockIdx.x, t = threadIdx.x;
  float v = x[(size_t)token * DMOD + t];
  float s = v;
#pragma unroll
  for (int o = 32; o; o >>= 1) s += __shfl_down(s, o, 64);
  int lane = t & 63, wid = t >> 6;
  if (lane == 0) red[wid] = s;
  __syncthreads();
  float mu = (red[0] + red[1] + red[2] + red[3]) * (1.f / 256.f);
  float dv = v - mu;
  s = dv * dv;
#pragma unroll
  for (int o = 32; o; o >>= 1) s += __shfl_down(s, o, 64);
  __syncthreads();
  if (lane == 0) red[wid] = s;
  __syncthreads();
  float var = (red[0] + red[1] + red[2] + red[3]) * (1.f / 256.f);
  out[(size_t)token * DMOD + t] = (_Float16)(dv * rsqrtf(var + 1e-5f) * w[t] + b[t]);
}

// ---------------- depthwise causal conv4 + bias + silu ----------------
__global__ __launch_bounds__(256) void conv_k(const float* __restrict__ big, const float* __restrict__ cw,
                                              const float* __restrict__ cb, float* __restrict__ ucv) {
  int i = blockIdx.x * 256 + threadIdx.x; // BL*DIN
  int token = i >> 9, c = i & 511;
  int b = token >> 9, l = token & 511;
  float acc = cb[c];
#pragma unroll
  for (int k = 0; k < 4; k++) {
    int l2 = l - 3 + k;
    if (l2 >= 0) acc += big[((size_t)(b * LSEQ + l2)) * 1024 + c] * cw[c * 4 + k];
  }
  ucv[i] = siluf_(acc);
}

// ---------------- xproj: u(512) -> 48 per token ----------------
__global__ __launch_bounds__(64) void xproj_k(const float* __restrict__ u, const float* __restrict__ W,
                                              float* __restrict__ xd) {
  int token = blockIdx.x;
  __shared__ float us[512];
  for (int j = threadIdx.x; j < 512; j += 64) us[j] = u[(size_t)token * DIN + j];
  __syncthreads();
  int t = threadIdx.x;
  if (t < 48) {
    float acc = 0.f;
    for (int c = 0; c < 512; c++) acc += us[c] * W[c * 48 + t];
    xd[token * 48 + t] = acc;
  }
}

// ---------------- dtproj + softplus ----------------
__global__ __launch_bounds__(256) void dtproj_k(const float* __restrict__ xd, const float* __restrict__ W,
                                                const float* __restrict__ bias, float* __restrict__ dt) {
  int i = blockIdx.x * 256 + threadIdx.x; // BL*DIN
  int token = i >> 9, c = i & 511;
  float acc = bias[c];
  const float* xr = xd + (size_t)token * 48;
#pragma unroll
  for (int r = 0; r < 16; r++) acc += xr[r] * W[r * 512 + c];
  float sp = (acc > 20.f) ? acc : log1pf(__expf(acc));
  dt[i] = sp;
}

// ---------------- chunked parallel scan ----------------
__global__ __launch_bounds__(256) void scanA_k(const float* __restrict__ dt, const float* __restrict__ ucv,
                                               const float* __restrict__ xd, const float* __restrict__ A_log,
                                               float* __restrict__ Pbuf, float* __restrict__ Hbuf) {
  int tid = blockIdx.x * 256 + threadIdx.x;
  int n = tid & 15;
  int c = (tid >> 4) & (NCHK - 1);
  int ch = tid >> 8;
  int b = ch >> 9, d = ch & 511;
  float An = -__expf(A_log[d * 16 + n]);
  float P = 1.f, h = 0.f;
  int t0 = b * LSEQ + c * CHUNK;
  for (int t = 0; t < CHUNK; t++) {
    int token = t0 + t;
    float dtv = dt[(size_t)token * DIN + d];
    float uv = ucv[(size_t)token * DIN + d];
    float Bn = xd[token * 48 + 16 + n];
    float dA = __expf(dtv * An);
    P *= dA;
    h = dA * h + (dtv * uv) * Bn;
  }
  Pbuf[tid] = P;
  Hbuf[tid] = h;
}

__global__ __launch_bounds__(256) void scanB_k(const float* __restrict__ Pbuf, const float* __restrict__ Hbuf,
                                               float* __restrict__ Hin) {
  int tid = blockIdx.x * 256 + threadIdx.x;
  int n = tid & 15;
  int ch = tid >> 4;
  float h = 0.f;
#pragma unroll
  for (int c = 0; c < NCHK; c++) {
    int idx = ch * (NCHK * 16) + c * 16 + n;
    Hin[idx] = h;
    h = Pbuf[idx] * h + Hbuf[idx];
  }
}

__global__ __launch_bounds__(256) void scanC_k(const float* __restrict__ dt, const float* __restrict__ ucv,
                                               const float* __restrict__ xd, const float* __restrict__ zbuf,
                                               const float* __restrict__ A_log, const float* __restrict__ D_p,
                                               const float* __restrict__ Hin, _Float16* __restrict__ gout) {
  int tid = blockIdx.x * 256 + threadIdx.x;
  int n = tid & 15;
  int c = (tid >> 4) & (NCHK - 1);
  int ch = tid >> 8;
  int b = ch >> 9, d = ch & 511;
  float An = -__expf(A_log[d * 16 + n]);
  float Dd = D_p[d];
  float h = Hin[tid];
  int t0 = b * LSEQ + c * CHUNK;
  for (int t = 0; t < CHUNK; t++) {
    int token = t0 + t;
    float dtv = dt[(size_t)token * DIN + d];
    float uv = ucv[(size_t)token * DIN + d];
    float Bn = xd[token * 48 + 16 + n];
    float Cn = xd[token * 48 + 32 + n];
    float dA = __expf(dtv * An);
    h = dA * h + (dtv * uv) * Bn;
    float y = h * Cn;
    y += __shfl_xor(y, 1, 64);
    y += __shfl_xor(y, 2, 64);
    y += __shfl_xor(y, 4, 64);
    y += __shfl_xor(y, 8, 64);
    if (n == 0) {
      float z = zbuf[(size_t)token * 1024 + 512 + d];
      gout[(size_t)token * DIN + d] = (_Float16)((y + uv * Dd) * siluf_(z));
    }
  }
}

// ---------------- SwiGLU for mlp: silu(g1)*g2 -> f16 ----------------
__global__ __launch_bounds__(256) void silumul_k(const float* __restrict__ big, _Float16* __restrict__ out) {
  int i = blockIdx.x * 256 + threadIdx.x; // BL*256
  int token = i >> 8, j = i & 255;
  float g1 = big[(size_t)token * 512 + j];
  float g2 = big[(size_t)token * 512 + 256 + j];
  out[i] = (_Float16)(siluf_(g1) * g2);
}

// ---------------- dueling heads ----------------
__device__ __forceinline__ float bred512(float v, float* red) {
  int lane = threadIdx.x & 63, wid = threadIdx.x >> 6;
#pragma unroll
  for (int o = 32; o; o >>= 1) v += __shfl_down(v, o, 64);
  __syncthreads();
  if (lane == 0) red[wid] = v;
  __syncthreads();
  float s = 0.f;
#pragma unroll
  for (int k = 0; k < 8; k++) s += red[k];
  return s;
}

__global__ __launch_bounds__(512) void head_k(
    const float* __restrict__ h, const float* __restrict__ nfw, const float* __restrict__ nfb,
    const float* vW1, const float* vb1, const float* vl1w, const float* vl1b,
    const float* vW2, const float* vb2, const float* vl2w, const float* vl2b,
    const float* vW3, const float* vb3,
    const float* aW1, const float* ab1, const float* al1w, const float* al1b,
    const float* aW2, const float* ab2, const float* al2w, const float* al2b,
    const float* aW3, const float* ab3, float* __restrict__ q) {
  __shared__ float f[256], t1[512], t2[256], red[8], outs[8];
  int b = blockIdx.x, t = threadIdx.x;
  const float* hr = h + ((size_t)b * LSEQ + (LSEQ - 1)) * DMOD;
  float v = (t < 256) ? hr[t] : 0.f;
  float mu = bred512(v, red) * (1.f / 256.f);
  float dv = (t < 256) ? (v - mu) : 0.f;
  float var = bred512(dv * dv, red) * (1.f / 256.f);
  if (t < 256) f[t] = dv * rsqrtf(var + 1e-5f) * nfw[t] + nfb[t];
  __syncthreads();
  for (int p = 0; p < 2; p++) {
    const float* W1 = p ? aW1 : vW1; const float* b1 = p ? ab1 : vb1;
    const float* l1w = p ? al1w : vl1w; const float* l1b = p ? al1b : vl1b;
    const float* W2 = p ? aW2 : vW2; const float* b2 = p ? ab2 : vb2;
    const float* l2w = p ? al2w : vl2w; const float* l2b = p ? al2b : vl2b;
    const float* W3 = p ? aW3 : vW3; const float* b3 = p ? ab3 : vb3;
    float a1 = b1[t];
    for (int j = 0; j < 256; j++) a1 += f[j] * W1[j * 512 + t];
    mu = bred512(a1, red) * (1.f / 512.f);
    dv = a1 - mu;
    var = bred512(dv * dv, red) * (1.f / 512.f);
    t1[t] = fmaxf(dv * rsqrtf(var + 1e-5f) * l1w[t] + l1b[t], 0.f);
    __syncthreads();
    float a2 = 0.f;
    if (t < 256) { a2 = b2[t]; for (int j = 0; j < 512; j++) a2 += t1[j] * W2[j * 256 + t]; }
    mu = bred512((t < 256) ? a2 : 0.f, red) * (1.f / 256.f);
    dv = (t < 256) ? (a2 - mu) : 0.f;
    var = bred512(dv * dv, red) * (1.f / 256.f);
    if (t < 256) t2[t] = fmaxf(dv * rsqrtf(var + 1e-5f) * l2w[t] + l2b[t], 0.f);
    __syncthreads();
    int nout = p ? 5 : 1;
    if (t < nout) {
      float a3 = b3[t];
      for (int j = 0; j < 256; j++) a3 += t2[j] * W3[j * nout + t];
      if (p == 0) outs[6] = a3; else outs[t] = a3;
    }
    __syncthreads();
  }
  if (t == 0) outs[7] = (outs[0] + outs[1] + outs[2] + outs[3] + outs[4]) * 0.2f;
  __syncthreads();
  if (t < 5) q[b * 5 + t] = outs[6] + outs[t] - outs[7];
}

extern "C" void kernel_launch(void* const* d_in, const int* in_sizes, int n_in,
                              void* d_out, int out_size, void* d_ws, size_t ws_size,
                              hipStream_t stream) {
  const float* src = (const float*)d_in[0];
  const float* tau = (const float*)d_in[1];
  const float* dain_Wm = (const float*)d_in[2];
  const float* dain_Ws = (const float*)d_in[3];
  const float* dain_Wg = (const float*)d_in[4];
  const float* dain_bg = (const float*)d_in[5];
  const float* memb_W = (const float*)d_in[6];
  const float* memb_b = (const float*)d_in[7];
  const float* t_w0 = (const float*)d_in[8];
  const float* t_b0 = (const float*)d_in[9];
  const float* t_w = (const float*)d_in[10];
  const float* t_b = (const float*)d_in[11];
  const float* tproj_W = (const float*)d_in[12];
  const float* tproj_b = (const float*)d_in[13];
  const float* ffn_W1 = (const float*)d_in[14];
  const float* ffn_b1 = (const float*)d_in[15];
  const float* ffn_W2 = (const float*)d_in[16];
  const float* ffn_b2 = (const float*)d_in[17];
  const float* n1_w = (const float*)d_in[18];
  const float* n1_b = (const float*)d_in[19];
  const float* inproj_W = (const float*)d_in[20];
  const float* conv_w = (const float*)d_in[21];
  const float* conv_b = (const float*)d_in[22];
  const float* xproj_W = (const float*)d_in[23];
  const float* dtproj_W = (const float*)d_in[24];
  const float* dt_bias = (const float*)d_in[25];
  const float* A_log = (const float*)d_in[26];
  const float* D_p = (const float*)d_in[27];
  const float* outproj_W = (const float*)d_in[28];
  const float* n2_w = (const float*)d_in[29];
  const float* n2_b = (const float*)d_in[30];
  const float* mlp_W1 = (const float*)d_in[31];
  const float* mlp_W2 = (const float*)d_in[32];
  const float* nf_w = (const float*)d_in[33];
  const float* nf_b = (const float*)d_in[34];
  const float* vW1 = (const float*)d_in[35]; const float* vb1 = (const float*)d_in[36];
  const float* vl1w = (const float*)d_in[37]; const float* vl1b = (const float*)d_in[38];
  const float* vW2 = (const float*)d_in[39]; const float* vb2 = (const float*)d_in[40];
  const float* vl2w = (const float*)d_in[41]; const float* vl2b = (const float*)d_in[42];
  const float* vW3 = (const float*)d_in[43]; const float* vb3 = (const float*)d_in[44];
  const float* aW1 = (const float*)d_in[45]; const float* ab1 = (const float*)d_in[46];
  const float* al1w = (const float*)d_in[47]; const float* al1b = (const float*)d_in[48];
  const float* aW2 = (const float*)d_in[49]; const float* ab2 = (const float*)d_in[50];
  const float* al2w = (const float*)d_in[51]; const float* al2b = (const float*)d_in[52];
  const float* aW3 = (const float*)d_in[53]; const float* ab3 = (const float*)d_in[54];
  float* out = (float*)d_out;

  float* ws = (float*)d_ws;
  float* stats = ws;                            // 256
  float* h    = stats + 256;                    // 524288
  float* big  = h + (size_t)BL * DMOD;          // 2883584 (max stride 1408)
  float* ucv  = big + (size_t)BL * 1408;        // 1048576
  float* xd   = ucv + (size_t)BL * DIN;         // 98304
  float* dt   = xd + (size_t)BL * 48;           // 1048576
  float* Pbuf = dt + (size_t)BL * DIN;          // 524288
  float* Hbuf = Pbuf + (size_t)NCH * NCHK * 16; // 524288
  float* Hin  = Hbuf + (size_t)NCH * NCHK * 16; // 524288
  float* fp_end = Hin + (size_t)NCH * NCHK * 16;
  // f16 arenas
  _Float16* h_hf   = (_Float16*)fp_end;            // BL*256
  _Float16* hn_hf  = h_hf + (size_t)BL * DMOD;     // BL*256
  _Float16* mid_hf = hn_hf + (size_t)BL * DMOD;    // BL*704
  _Float16* gout_hf = mid_hf + (size_t)BL * 704;   // BL*512
  _Float16* ffn1T  = gout_hf + (size_t)BL * DIN;   // 1408*256
  _Float16* ffn2T  = ffn1T + (size_t)1408 * 256;   // 256*704
  _Float16* inprojT = ffn2T + (size_t)256 * 704;   // 8*1024*256
  _Float16* outprojT = inprojT + (size_t)8 * 1024 * 256; // 8*256*512
  _Float16* mlp1T  = outprojT + (size_t)8 * 256 * 512;   // 8*512*256
  _Float16* mlp2T  = mlp1T + (size_t)8 * 512 * 256;      // 8*256*256

  // ---- weight conversions (every call; ~11MB, L2/L3-resident) ----
  convT_k<<<dim3(1408, 1), 256, 0, stream>>>(ffn_W1, ffn1T, 256, 1364, 256, 1408);
  convT_k<<<dim3(704, 1), 256, 0, stream>>>(ffn_W2, ffn2T, 682, 256, 704, 256);
  convT_k<<<dim3(1024, 8), 256, 0, stream>>>(inproj_W, inprojT, 256, 1024, 256, 1024);
  convT_k<<<dim3(512, 8), 256, 0, stream>>>(outproj_W, outprojT, 512, 256, 512, 256);
  convT_k<<<dim3(512, 8), 256, 0, stream>>>(mlp_W1, mlp1T, 256, 512, 256, 512);
  convT_k<<<dim3(256, 8), 256, 0, stream>>>(mlp_W2, mlp2T, 256, 256, 256, 256);

  dain_k<<<1, 1024, 0, stream>>>(src, dain_Wm, dain_Ws, dain_Wg, dain_bg, stats);
  embed_k<<<BL, 256, 0, stream>>>(src, tau, stats, memb_W, memb_b, t_w0, t_b0, t_w, t_b, tproj_W, tproj_b, h, h_hf);
  gemm_hf_k<<<dim3(22, 32), 256, 0, stream>>>(h_hf, ffn1T, ffn_b1, big, BL, 1364, 256, 1364, 0);
  glugelu_k<<<BL * 704 / 256, 256, 0, stream>>>(big, mid_hf);
  gemm_hf_k<<<dim3(4, 32), 256, 0, stream>>>(mid_hf, ffn2T, ffn_b2, h, BL, 256, 704, 256, 0);

  const int scanAC_blocks = NCH * NCHK * 16 / 256; // 2048
  for (int i = 0; i < 8; i++) {
    ln_k<<<BL, 256, 0, stream>>>(h, n1_w + i * 256, n1_b + i * 256, hn_hf);
    gemm_hf_k<<<dim3(16, 32), 256, 0, stream>>>(hn_hf, inprojT + (size_t)i * 1024 * 256, nullptr, big,
                                                BL, 1024, 256, 1024, 0);
    conv_k<<<BL * DIN / 256, 256, 0, stream>>>(big, conv_w + (size_t)i * 512 * 4, conv_b + i * 512, ucv);
    xproj_k<<<BL, 64, 0, stream>>>(ucv, xproj_W + (size_t)i * 512 * 48, xd);
    dtproj_k<<<BL * DIN / 256, 256, 0, stream>>>(xd, dtproj_W + (size_t)i * 16 * 512, dt_bias + i * 512, dt);
    scanA_k<<<scanAC_blocks, 256, 0, stream>>>(dt, ucv, xd, A_log + (size_t)i * 512 * 16, Pbuf, Hbuf);
    scanB_k<<<NCH * 16 / 256, 256, 0, stream>>>(Pbuf, Hbuf, Hin);
    scanC_k<<<scanAC_blocks, 256, 0, stream>>>(dt, ucv, xd, big, A_log + (size_t)i * 512 * 16,
                                               D_p + i * 512, Hin, gout_hf);
    gemm_hf_k<<<dim3(4, 32), 256, 0, stream>>>(gout_hf, outprojT + (size_t)i * 256 * 512, nullptr, h,
                                               BL, 256, 512, 256, 1);
    ln_k<<<BL, 256, 0, stream>>>(h, n2_w + i * 256, n2_b + i * 256, hn_hf);
    gemm_hf_k<<<dim3(8, 32), 256, 0, stream>>>(hn_hf, mlp1T + (size_t)i * 512 * 256, nullptr, big,
                                               BL, 512, 256, 512, 0);
    silumul_k<<<BL, 256, 0, stream>>>(big, mid_hf);
    gemm_hf_k<<<dim3(4, 32), 256, 0, stream>>>(mid_hf, mlp2T + (size_t)i * 256 * 256, nullptr, h,
                                               BL, 256, 256, 256, 1);
  }

  head_k<<<NB, 512, 0, stream>>>(h, nf_w, nf_b,
                                 vW1, vb1, vl1w, vl1b, vW2, vb2, vl2w, vl2b, vW3, vb3,
                                 aW1, ab1, al1w, al1b, aW2, ab2, al2w, al2b, aW3, ab3, out);
  (void)in_sizes; (void)n_in; (void)out_size; (void)ws_size;
}